// Round 5
// baseline (1879.712 us; speedup 1.0000x reference)
//
#include <hip/hip_runtime.h>
#include <cstdint>
#include <cstddef>

#define B_ 4
#define T_ 2048
#define D_ 2048
#define H_ 16

typedef __bf16 bf16x8 __attribute__((ext_vector_type(8)));
typedef float  f32x4  __attribute__((ext_vector_type(4)));
typedef unsigned short u16;
typedef u16 u16x8 __attribute__((ext_vector_type(8)));

__device__ __forceinline__ u16 f2bf(float f) {
    union { float f; unsigned u; } v; v.f = f;
    unsigned r = v.u + 0x7FFFu + ((v.u >> 16) & 1u);
    return (u16)(r >> 16);
}
__device__ __forceinline__ float bf2f(u16 h) {
    union { unsigned u; float f; } v; v.u = ((unsigned)h) << 16;
    return v.f;
}
__device__ __forceinline__ float sigmoidf_(float x) {
    return 1.f / (1.f + __expf(-x));
}
__device__ __forceinline__ void async_load16(const void* g, void* l) {
    __builtin_amdgcn_global_load_lds(
        (const __attribute__((address_space(1))) void*)g,
        (__attribute__((address_space(3))) void*)l,
        16, 0, 0);
}

// 16-lane all-reduce sum via DPP (within each DPP row of 16 lanes)
// quad_perm xor1 -> quad_perm xor2 -> row_mirror -> row_half_mirror  (HW-verified r1)
__device__ __forceinline__ float row_allreduce16(float x) {
    int v;
    v = __builtin_amdgcn_update_dpp(0, __builtin_bit_cast(int, x), 0xB1, 0xF, 0xF, true);
    x += __builtin_bit_cast(float, v);
    v = __builtin_amdgcn_update_dpp(0, __builtin_bit_cast(int, x), 0x4E, 0xF, 0xF, true);
    x += __builtin_bit_cast(float, v);
    v = __builtin_amdgcn_update_dpp(0, __builtin_bit_cast(int, x), 0x140, 0xF, 0xF, true);
    x += __builtin_bit_cast(float, v);
    v = __builtin_amdgcn_update_dpp(0, __builtin_bit_cast(int, x), 0x141, 0xF, 0xF, true);
    x += __builtin_bit_cast(float, v);
    return x;
}

// 32-lane group all-reduce; groups = {rows 0,2} and {rows 1,3} (lane l grouped with l^32).
// Cross-row step via __shfl_xor(.,32) — harness-verified (r3 passed).
__device__ __forceinline__ float grp32_allreduce(float x) {
    x = row_allreduce16(x);
    x += __shfl_xor(x, 32);
    return x;
}

// ---------------------------------------------------------------- f32 -> bf16 convert (x4 vectorized; n % 4 == 0)
__global__ void cvt_bf16_k(const float* __restrict__ s, u16* __restrict__ d, int n) {
    int i = blockIdx.x * 256 + threadIdx.x;   // element-group index
    if (i * 4 < n) {
        float4 v = *(const float4*)(s + (size_t)i * 4);
        ushort4 o = {f2bf(v.x), f2bf(v.y), f2bf(v.z), f2bf(v.w)};
        *(ushort4*)(d + (size_t)i * 4) = o;
    }
}

// ---------------------------------------------------------------- Wb pad: f32 (16,2048) -> bf16 (128,2048), rows 16..127 zero
__global__ void pad_wb_k(const float* __restrict__ Wb, u16* __restrict__ d) {
    int i = blockIdx.x * 256 + threadIdx.x;   // 262144 total
    d[i] = (i < 32768) ? f2bf(Wb[i]) : (u16)0;
}

// ---------------------------------------------------------------- GEMM (C = A * B^T), bf16 in, m97-style
// PERM=1: permute output column within each 128-block: ch -> (ch&31)*4 + (ch>>5)
// (scan layout: lane kidx's 4 channels {kidx,kidx+32,kidx+64,kidx+96} land contiguous)
__device__ __forceinline__ void store_c(float* p, float v) { *p = v; }
__device__ __forceinline__ void store_c(u16* p, float v) { *p = f2bf(v); }

template <typename OutT, int PERM>
__global__ __launch_bounds__(256) void gemm_bt(const u16* __restrict__ A,
                                               const u16* __restrict__ Bm,
                                               OutT* __restrict__ C, int K, int ldc) {
    __shared__ __align__(16) u16 smA[128 * 64];
    __shared__ __align__(16) u16 smB[128 * 64];
    const int tid  = threadIdx.x;
    const int lane = tid & 63;
    const int w    = tid >> 6;
    const int wm   = (w >> 1) * 64;
    const int wn   = (w & 1) * 64;
    const int bm   = blockIdx.x, bn = blockIdx.y;

    f32x4 acc[4][4];
#pragma unroll
    for (int i = 0; i < 4; ++i)
#pragma unroll
        for (int j = 0; j < 4; ++j) acc[i][j] = (f32x4){0.f, 0.f, 0.f, 0.f};

    const int rr = tid >> 3;            // 0..31
    const int cc = (tid & 7) * 8;       // 0..56
    const u16* Ag = A + (size_t)(bm * 128) * K;
    const u16* Bg = Bm + (size_t)(bn * 128) * K;

    for (int k0 = 0; k0 < K; k0 += 64) {
#pragma unroll
        for (int it = 0; it < 4; ++it) {
            async_load16(Ag + (size_t)(it * 32 + rr) * K + (k0 + cc), &smA[(it * 256 + tid) * 8]);
            async_load16(Bg + (size_t)(it * 32 + rr) * K + (k0 + cc), &smB[(it * 256 + tid) * 8]);
        }
        __syncthreads();
#pragma unroll
        for (int kk = 0; kk < 64; kk += 32) {
            bf16x8 af[4], bfr[4];
            const int qoff = kk + ((lane >> 4) * 8);
#pragma unroll
            for (int mi = 0; mi < 4; ++mi)
                af[mi] = *(const bf16x8*)&smA[(wm + mi * 16 + (lane & 15)) * 64 + qoff];
#pragma unroll
            for (int ni = 0; ni < 4; ++ni)
                bfr[ni] = *(const bf16x8*)&smB[(wn + ni * 16 + (lane & 15)) * 64 + qoff];
#pragma unroll
            for (int mi = 0; mi < 4; ++mi)
#pragma unroll
                for (int ni = 0; ni < 4; ++ni)
                    acc[mi][ni] = __builtin_amdgcn_mfma_f32_16x16x32_bf16(af[mi], bfr[ni], acc[mi][ni], 0, 0, 0);
        }
        __syncthreads();
    }

#pragma unroll
    for (int mi = 0; mi < 4; ++mi) {
        const int row0 = bm * 128 + wm + mi * 16 + ((lane >> 4) * 4);
#pragma unroll
        for (int ni = 0; ni < 4; ++ni) {
            int colg = bn * 128 + wn + ni * 16 + (lane & 15);
            if (PERM) {
                int cl = colg & 127;
                colg = (colg & ~127) | (((cl & 31) << 2) | (cl >> 5));
            }
#pragma unroll
            for (int rg = 0; rg < 4; ++rg)
                store_c(&C[(size_t)(row0 + rg) * ldc + colg], acc[mi][ni][rg]);
        }
    }
}

// ---------------------------------------------------------------- causal depthwise conv(K=4) + bias + SiLU
// in : pre bf16 (B*T, 2048), col = h*128+c ; w/bias f32
// out: bf16 [(b*H+h)*T + t]*128 + p ; p = cl (TRANSPOSE=0) or scan layout (TRANSPOSE=1)
template <int TRANSPOSE>
__global__ void conv_silu_k(const u16* __restrict__ pre,
                            const float* __restrict__ w, const float* __restrict__ bias,
                            u16* __restrict__ outp) {
    int idx = blockIdx.x * 256 + threadIdx.x;          // B*T*2048 = 2^24 exact
    int c = idx & 2047;
    int t = (idx >> 11) & (T_ - 1);
    int b = idx >> 22;
    const u16* base = pre + (size_t)(b * T_ + t) * 2048 + c;
    float acc = bias[c];
#pragma unroll
    for (int j = 0; j < 4; ++j) {
        int tt = t - 3 + j;
        if (tt >= 0) {
            float xv = bf2f(base[(ptrdiff_t)(j - 3) * 2048]);
            acc = fmaf(xv, w[c * 4 + j], acc);
        }
    }
    float y = acc * sigmoidf_(acc);                    // SiLU
    int h = c >> 7, cl = c & 127;
    int p = TRANSPOSE ? (((cl & 31) << 2) | (cl >> 5)) : cl;
    outp[((size_t)(b * H_ + h) * T_ + t) * 128 + p] = f2bf(y);
}

// ---------------------------------------------------------------- gated delta-rule scan v3
// 512 blocks x 512 threads, XCD-clustered (as r3). Per v-column: 32 lanes, 4 ch/lane.
// CHANGE vs r3 (which was LDS-pipe-bound: 60 LDS-cy/step/wave x 16 waves/CU = 818 us model
// ~ 755 us measured): q,k,v are now PER-LANE GLOBAL loads (scan layout; lane's 4 channels
// = one ushort4), ring-prefetched 4 steps ahead with static slot indexing. Only d (sigmoid
// amortized across 512 threads) and beta stay LDS-staged. LDS/step: 12(d)+6(beta)+12(shfl).
// Numerics bit-identical to r3.
#define TB2 16
__global__ __launch_bounds__(512, 4) void kda_scan_k(const u16* __restrict__ qg,
                                                     const u16* __restrict__ kg,
                                                     const u16* __restrict__ vg,
                                                     const u16* __restrict__ ag,   // a pre-act bf16 (B*T,2048), scan layout per head-block
                                                     const u16* __restrict__ bpg,  // beta pre-act bf16 (B*T,128)
                                                     const float* __restrict__ bav, // ba f32 (2048), ORIGINAL channel order
                                                     const float* __restrict__ bbv, // bb f32 (16)
                                                     u16* __restrict__ og) {
    const int blk = blockIdx.x;
    // XCD-clustered: xcd = blk&7 (round-robin dispatch); 8 bh per XCD, 8 vch-blocks per bh
    const int bh  = (blk & 7) * 8 + (blk >> 6);
    const int vch = (blk >> 3) & 7;
    const int tid = threadIdx.x;
    const int lane = tid & 63;
    const int w    = tid >> 6;                       // wave 0..7
    const int colIdx = w * 2 + ((lane >> 4) & 1);    // 0..15 (v-column within block)
    const int kidx   = (lane & 15) + ((lane >> 5) << 4);  // 0..31
    const int b = bh >> 4, h = bh & 15;

    __shared__ __align__(16) float sd[2][TB2][128];
    __shared__ float sb_[2][TB2];

    // per-lane global bases
    const u16* qb  = qg + (size_t)bh * T_ * 128 + kidx * 4;
    const u16* kb  = kg + (size_t)bh * T_ * 128 + kidx * 4;
    const u16* vb  = vg + (size_t)bh * T_ * 128 + vch * 16 + colIdx;
    const u16* ab  = ag + (size_t)b * T_ * 2048 + h * 128;
    const u16* bpb = bpg + (size_t)b * T_ * 128 + h;
    u16* op = og + (size_t)b * T_ * 2048 + h * 128 + vch * 16 + colIdx;

    // staging role for d: thread (ur, p4) covers scan-layout positions p4..p4+3 of timestep ur
    const int ur = tid >> 5;               // 0..15
    const int p4 = (tid & 31) * 4;
    // position p4+e is original channel ch = e*32 + (tid&31)
    const float rba0 = bav[h * 128 +  0 + (tid & 31)];
    const float rba1 = bav[h * 128 + 32 + (tid & 31)];
    const float rba2 = bav[h * 128 + 64 + (tid & 31)];
    const float rba3 = bav[h * 128 + 96 + (tid & 31)];
    const float bbh = bbv[h];

    float S[4];
#pragma unroll
    for (int j = 0; j < 4; ++j) S[j] = 0.f;

    // ring prefetch (distance 4) for q,k,v — all slot indices compile-time (full unroll)
    ushort4 rq4[4], rk4[4];
    u16 rv4[4];
#pragma unroll
    for (int i = 0; i < 4; ++i) {
        rq4[i] = *(const ushort4*)(qb + (size_t)i * 128);
        rk4[i] = *(const ushort4*)(kb + (size_t)i * 128);
        rv4[i] = vb[(size_t)i * 128];
    }

    // staging prefetch regs for d (a pre-act) and beta, tile 0
    ushort4 ra = *(const ushort4*)(ab + (size_t)ur * 2048 + p4);
    float rbet = (tid < TB2) ? bf2f(bpb[(size_t)tid * 128]) : 0.f;

    const float scale = 0.08838834764831845f;  // 128^-0.5
    const int NM = T_ / TB2;
    for (int m = 0; m < NM; ++m) {
        const int pb = m & 1;
        float4 fd = {fmaxf(sigmoidf_(bf2f(ra.x) + rba0), 1e-6f),
                     fmaxf(sigmoidf_(bf2f(ra.y) + rba1), 1e-6f),
                     fmaxf(sigmoidf_(bf2f(ra.z) + rba2), 1e-6f),
                     fmaxf(sigmoidf_(bf2f(ra.w) + rba3), 1e-6f)};
        *(float4*)&sd[pb][ur][p4] = fd;
        if (tid < TB2) sb_[pb][tid] = sigmoidf_(rbet + bbh);
        __syncthreads();
        if (m + 1 < NM) {
            size_t t0n = (size_t)(m + 1) * TB2;
            ra = *(const ushort4*)(ab + (t0n + ur) * 2048 + p4);
            if (tid < TB2) rbet = bf2f(bpb[(t0n + tid) * 128]);
        }
#pragma unroll
        for (int u = 0; u < TB2; ++u) {
            const int s = u & 3;                     // ring slot: t&3 == u&3
            const int t = m * TB2 + u;
            float4 q4 = {bf2f(rq4[s].x), bf2f(rq4[s].y), bf2f(rq4[s].z), bf2f(rq4[s].w)};
            float4 k4 = {bf2f(rk4[s].x), bf2f(rk4[s].y), bf2f(rk4[s].z), bf2f(rk4[s].w)};
            float fv = bf2f(rv4[s]);
            float4 d4 = *(const float4*)&sd[pb][u][kidx * 4];
            // refill slot with t+4 (clamped; clamped loads are consumed-never-used)
            int tn = t + 4; if (tn > T_ - 1) tn = T_ - 1;
            rq4[s] = *(const ushort4*)(qb + (size_t)tn * 128);
            rk4[s] = *(const ushort4*)(kb + (size_t)tn * 128);
            rv4[s] = vb[(size_t)tn * 128];

            float e0, e1;
            S[0] *= d4.x; e0 = k4.x * S[0];
            S[1] *= d4.y; e1 = k4.y * S[1];
            S[2] *= d4.z; e0 = fmaf(k4.z, S[2], e0);
            S[3] *= d4.w; e1 = fmaf(k4.w, S[3], e1);
            float errp = grp32_allreduce(e0 + e1);
            float uu = sb_[pb][u] * (fv - errp);
            float o0, o1;
            S[0] = fmaf(k4.x, uu, S[0]); o0 = q4.x * S[0];
            S[1] = fmaf(k4.y, uu, S[1]); o1 = q4.y * S[1];
            S[2] = fmaf(k4.z, uu, S[2]); o0 = fmaf(q4.z, S[2], o0);
            S[3] = fmaf(k4.w, uu, S[3]); o1 = fmaf(q4.w, S[3], o1);
            float outv = grp32_allreduce(o0 + o1);
            if (((lane & 15) | (lane >> 5)) == 0)      // lanes 0 (colIdx w*2) and 16 (w*2+1)
                op[(size_t)t * 2048] = f2bf(scale * outv);
        }
        __syncthreads();
    }
}

// ---------------------------------------------------------------- per-head LayerNorm * sigmoid-gate -> bf16 act
__global__ __launch_bounds__(256) void ln_gate_k(const u16* __restrict__ o,
                                                 const u16* __restrict__ gpre,
                                                 const float* __restrict__ lnw,
                                                 const float* __restrict__ lnb,
                                                 u16* __restrict__ act) {
    int inst = blockIdx.x * 4 + (threadIdx.x >> 6);  // (b*T+t)*16 + h
    int lane = threadIdx.x & 63;
    int bt = inst >> 4, h = inst & 15;
    const u16* opr = o + (size_t)bt * 2048 + h * 128;
    ushort2 xr = *(const ushort2*)(opr + lane * 2);
    float x0 = bf2f(xr.x), x1 = bf2f(xr.y);
    float s  = x0 + x1;
    float ss = x0 * x0 + x1 * x1;
#pragma unroll
    for (int msk = 1; msk < 64; msk <<= 1) {
        s  += __shfl_xor(s, msk);
        ss += __shfl_xor(ss, msk);
    }
    float mu   = s * (1.f / 128.f);
    float var  = ss * (1.f / 128.f) - mu * mu;
    float rstd = rsqrtf(var + 1e-5f);
    const u16* gp = gpre + (size_t)bt * 2048 + h * 128 + lane * 2;
    u16* ap = act + (size_t)bt * 2048 + h * 128 + lane * 2;
#pragma unroll
    for (int e = 0; e < 2; ++e) {
        int v = lane * 2 + e;
        float xx = (e == 0) ? x0 : x1;
        float y = (xx - mu) * rstd * lnw[v] + lnb[v];
        float gate = sigmoidf_(bf2f(gp[e]));
        ap[e] = f2bf(y * gate);
    }
}

// ---------------------------------------------------------------- launch
// Tensors are FLOAT32 (per reference). bf16 only as internal GEMM operands.
// ws = 144.7 MB: Wslot(8M bf16) qpre/kpre/vpre/apre(32M bf16 each) bpre(2M).
// d_out (64MB f32) doubles as scratch: lo 32MB = xb (x in bf16), hi 32MB = qsc.
// Buffer lifetimes (stream-serialized):
//   gemms q,k,v,a,beta (read xb) -> conv q->qsc, k->ksc(=qpre), v->vsc(=kpre)
//   -> scan(qsc,ksc,vsc,apre,bpre)->ob(=vpre) -> gemm g (reads xb)->gpre(=qpre)
//   -> ln_gate(ob,gpre)->act(=kpre) -> gemm o (reads act)->d_out (f32).
extern "C" void kernel_launch(void* const* d_in, const int* in_sizes, int n_in,
                              void* d_out, int out_size, void* d_ws, size_t ws_size,
                              hipStream_t stream) {
    (void)in_sizes; (void)n_in; (void)out_size; (void)ws_size;
    const float* x   = (const float*)d_in[0];
    const float* Wq  = (const float*)d_in[1];
    const float* Wk  = (const float*)d_in[2];
    const float* Wv  = (const float*)d_in[3];
    const float* Wa  = (const float*)d_in[4];
    const float* ba  = (const float*)d_in[5];
    const float* Wb  = (const float*)d_in[6];
    const float* bbv = (const float*)d_in[7];
    const float* Wg  = (const float*)d_in[8];
    const float* Wo  = (const float*)d_in[9];
    const float* cqw = (const float*)d_in[10];
    const float* cqb = (const float*)d_in[11];
    const float* ckw = (const float*)d_in[12];
    const float* ckb = (const float*)d_in[13];
    const float* cvw = (const float*)d_in[14];
    const float* cvb = (const float*)d_in[15];
    const float* lnw = (const float*)d_in[16];
    const float* lnb = (const float*)d_in[17];
    float* out = (float*)d_out;

    char* p = (char*)d_ws;
    size_t off = 0;
    auto take = [&](size_t bytes) -> char* {
        char* r = p + off;
        off += (bytes + 255) & ~(size_t)255;
        return r;
    };
    u16* Wslot = (u16*)take((size_t)4194304 * 2);
    u16* qpre  = (u16*)take((size_t)16777216 * 2);
    u16* kpre  = (u16*)take((size_t)16777216 * 2);
    u16* vpre  = (u16*)take((size_t)16777216 * 2);
    u16* apre  = (u16*)take((size_t)16777216 * 2);
    u16* bpre  = (u16*)take((size_t)1048576 * 2);

    u16* xb  = (u16*)d_out;                 // lo 32MB of d_out
    u16* qsc = (u16*)d_out + 16777216;      // hi 32MB of d_out
    u16* ksc  = qpre;   // after conv-q
    u16* vsc  = kpre;   // after conv-k
    u16* ob   = vpre;   // after conv-v
    u16* gpre = qpre;   // after scan
    u16* act  = kpre;   // after scan (vsc dead)

    // x -> bf16 (into d_out lo half)
    cvt_bf16_k<<<16384, 256, 0, stream>>>(x, xb, 16777216);

    // projections: convert weight into Wslot, then GEMM (C = A @ B^T)
    cvt_bf16_k<<<4096, 256, 0, stream>>>(Wq, Wslot, 4194304);
    gemm_bt<u16, 0><<<dim3(64, 16), 256, 0, stream>>>(xb, Wslot, qpre, 2048, 2048);
    cvt_bf16_k<<<4096, 256, 0, stream>>>(Wk, Wslot, 4194304);
    gemm_bt<u16, 0><<<dim3(64, 16), 256, 0, stream>>>(xb, Wslot, kpre, 2048, 2048);
    cvt_bf16_k<<<4096, 256, 0, stream>>>(Wv, Wslot, 4194304);
    gemm_bt<u16, 0><<<dim3(64, 16), 256, 0, stream>>>(xb, Wslot, vpre, 2048, 2048);
    cvt_bf16_k<<<4096, 256, 0, stream>>>(Wa, Wslot, 4194304);
    gemm_bt<u16, 1><<<dim3(64, 16), 256, 0, stream>>>(xb, Wslot, apre, 2048, 2048);  // scan layout
    pad_wb_k<<<1024, 256, 0, stream>>>(Wb, Wslot);
    gemm_bt<u16, 0><<<dim3(64, 1), 256, 0, stream>>>(xb, Wslot, bpre, 2048, 128);

    // conv + SiLU + layout change (q,k scan layout; v standard)
    conv_silu_k<1><<<65536, 256, 0, stream>>>(qpre, cqw, cqb, qsc);
    conv_silu_k<1><<<65536, 256, 0, stream>>>(kpre, ckw, ckb, ksc);
    conv_silu_k<0><<<65536, 256, 0, stream>>>(vpre, cvw, cvb, vsc);

    // sequential gated delta-rule scan (decay/beta computed in-kernel)
    kda_scan_k<<<512, 512, 0, stream>>>(qsc, ksc, vsc, apre, bpre, ba, bbv, ob);

    // gate projection (deferred; xb still intact in d_out lo half)
    cvt_bf16_k<<<4096, 256, 0, stream>>>(Wg, Wslot, 4194304);
    gemm_bt<u16, 0><<<dim3(64, 16), 256, 0, stream>>>(xb, Wslot, gpre, 2048, 2048);

    // LayerNorm * gate -> bf16 activations
    ln_gate_k<<<32768, 256, 0, stream>>>(ob, gpre, lnw, lnb, act);

    // output projection -> f32 out (overwrites xb/qsc scratch)
    cvt_bf16_k<<<4096, 256, 0, stream>>>(Wo, Wslot, 4194304);
    gemm_bt<float, 0><<<dim3(64, 16), 256, 0, stream>>>(act, Wslot, out, 2048, 2048);
}

// Round 6
// 1694.104 us; speedup vs baseline: 1.1096x; 1.1096x over previous
//
#include <hip/hip_runtime.h>
#include <cstdint>
#include <cstddef>

#define B_ 4
#define T_ 2048
#define D_ 2048
#define H_ 16

typedef __bf16 bf16x8 __attribute__((ext_vector_type(8)));
typedef float  f32x4  __attribute__((ext_vector_type(4)));
typedef unsigned short u16;
typedef u16 u16x8 __attribute__((ext_vector_type(8)));

__device__ __forceinline__ u16 f2bf(float f) {
    union { float f; unsigned u; } v; v.f = f;
    unsigned r = v.u + 0x7FFFu + ((v.u >> 16) & 1u);
    return (u16)(r >> 16);
}
__device__ __forceinline__ float bf2f(u16 h) {
    union { unsigned u; float f; } v; v.u = ((unsigned)h) << 16;
    return v.f;
}
__device__ __forceinline__ float sigmoidf_(float x) {
    return 1.f / (1.f + __expf(-x));
}
__device__ __forceinline__ void async_load16(const void* g, void* l) {
    __builtin_amdgcn_global_load_lds(
        (const __attribute__((address_space(1))) void*)g,
        (__attribute__((address_space(3))) void*)l,
        16, 0, 0);
}

// 16-lane all-reduce sum via DPP (within each DPP row of 16 lanes)
// quad_perm xor1 -> quad_perm xor2 -> row_mirror -> row_half_mirror  (HW-verified r1/r3/r5)
__device__ __forceinline__ float row_allreduce16(float x) {
    int v;
    v = __builtin_amdgcn_update_dpp(0, __builtin_bit_cast(int, x), 0xB1, 0xF, 0xF, true);
    x += __builtin_bit_cast(float, v);
    v = __builtin_amdgcn_update_dpp(0, __builtin_bit_cast(int, x), 0x4E, 0xF, 0xF, true);
    x += __builtin_bit_cast(float, v);
    v = __builtin_amdgcn_update_dpp(0, __builtin_bit_cast(int, x), 0x140, 0xF, 0xF, true);
    x += __builtin_bit_cast(float, v);
    v = __builtin_amdgcn_update_dpp(0, __builtin_bit_cast(int, x), 0x141, 0xF, 0xF, true);
    x += __builtin_bit_cast(float, v);
    return x;
}

// ---------------------------------------------------------------- f32 -> bf16 convert (x4 vectorized; n % 4 == 0)
__global__ void cvt_bf16_k(const float* __restrict__ s, u16* __restrict__ d, int n) {
    int i = blockIdx.x * 256 + threadIdx.x;   // element-group index
    if (i * 4 < n) {
        float4 v = *(const float4*)(s + (size_t)i * 4);
        ushort4 o = {f2bf(v.x), f2bf(v.y), f2bf(v.z), f2bf(v.w)};
        *(ushort4*)(d + (size_t)i * 4) = o;
    }
}

// ---------------------------------------------------------------- Wb pad: f32 (16,2048) -> bf16 (128,2048), rows 16..127 zero
__global__ void pad_wb_k(const float* __restrict__ Wb, u16* __restrict__ d) {
    int i = blockIdx.x * 256 + threadIdx.x;   // 262144 total
    d[i] = (i < 32768) ? f2bf(Wb[i]) : (u16)0;
}

// ---------------------------------------------------------------- GEMM (C = A * B^T), bf16 in, m97-style
// PERM=1 (r1-verified): permute output column within each 128-block: ch -> (ch&15)*8 + (ch>>4)
// (scan layout: lane sl's 8 channels {sl,sl+16,..,sl+112} land contiguous as 16B)
__device__ __forceinline__ void store_c(float* p, float v) { *p = v; }
__device__ __forceinline__ void store_c(u16* p, float v) { *p = f2bf(v); }

template <typename OutT, int PERM>
__global__ __launch_bounds__(256) void gemm_bt(const u16* __restrict__ A,
                                               const u16* __restrict__ Bm,
                                               OutT* __restrict__ C, int K, int ldc) {
    __shared__ __align__(16) u16 smA[128 * 64];
    __shared__ __align__(16) u16 smB[128 * 64];
    const int tid  = threadIdx.x;
    const int lane = tid & 63;
    const int w    = tid >> 6;
    const int wm   = (w >> 1) * 64;
    const int wn   = (w & 1) * 64;
    const int bm   = blockIdx.x, bn = blockIdx.y;

    f32x4 acc[4][4];
#pragma unroll
    for (int i = 0; i < 4; ++i)
#pragma unroll
        for (int j = 0; j < 4; ++j) acc[i][j] = (f32x4){0.f, 0.f, 0.f, 0.f};

    const int rr = tid >> 3;            // 0..31
    const int cc = (tid & 7) * 8;       // 0..56
    const u16* Ag = A + (size_t)(bm * 128) * K;
    const u16* Bg = Bm + (size_t)(bn * 128) * K;

    for (int k0 = 0; k0 < K; k0 += 64) {
#pragma unroll
        for (int it = 0; it < 4; ++it) {
            async_load16(Ag + (size_t)(it * 32 + rr) * K + (k0 + cc), &smA[(it * 256 + tid) * 8]);
            async_load16(Bg + (size_t)(it * 32 + rr) * K + (k0 + cc), &smB[(it * 256 + tid) * 8]);
        }
        __syncthreads();
#pragma unroll
        for (int kk = 0; kk < 64; kk += 32) {
            bf16x8 af[4], bfr[4];
            const int qoff = kk + ((lane >> 4) * 8);
#pragma unroll
            for (int mi = 0; mi < 4; ++mi)
                af[mi] = *(const bf16x8*)&smA[(wm + mi * 16 + (lane & 15)) * 64 + qoff];
#pragma unroll
            for (int ni = 0; ni < 4; ++ni)
                bfr[ni] = *(const bf16x8*)&smB[(wn + ni * 16 + (lane & 15)) * 64 + qoff];
#pragma unroll
            for (int mi = 0; mi < 4; ++mi)
#pragma unroll
                for (int ni = 0; ni < 4; ++ni)
                    acc[mi][ni] = __builtin_amdgcn_mfma_f32_16x16x32_bf16(af[mi], bfr[ni], acc[mi][ni], 0, 0, 0);
        }
        __syncthreads();
    }

#pragma unroll
    for (int mi = 0; mi < 4; ++mi) {
        const int row0 = bm * 128 + wm + mi * 16 + ((lane >> 4) * 4);
#pragma unroll
        for (int ni = 0; ni < 4; ++ni) {
            int colg = bn * 128 + wn + ni * 16 + (lane & 15);
            if (PERM) colg = (colg & ~127) | (((colg & 15) << 3) | ((colg >> 4) & 7));
#pragma unroll
            for (int rg = 0; rg < 4; ++rg)
                store_c(&C[(size_t)(row0 + rg) * ldc + colg], acc[mi][ni][rg]);
        }
    }
}

// ---------------------------------------------------------------- causal depthwise conv(K=4) + bias + SiLU
// in : pre bf16 (B*T, 2048), col = h*128+c ; w/bias f32
// out: bf16 [(b*H+h)*T + t]*128 + p ; p = cl (TRANSPOSE=0) or r1 scan layout (TRANSPOSE=1)
template <int TRANSPOSE>
__global__ void conv_silu_k(const u16* __restrict__ pre,
                            const float* __restrict__ w, const float* __restrict__ bias,
                            u16* __restrict__ outp) {
    int idx = blockIdx.x * 256 + threadIdx.x;          // B*T*2048 = 2^24 exact
    int c = idx & 2047;
    int t = (idx >> 11) & (T_ - 1);
    int b = idx >> 22;
    const u16* base = pre + (size_t)(b * T_ + t) * 2048 + c;
    float acc = bias[c];
#pragma unroll
    for (int j = 0; j < 4; ++j) {
        int tt = t - 3 + j;
        if (tt >= 0) {
            float xv = bf2f(base[(ptrdiff_t)(j - 3) * 2048]);
            acc = fmaf(xv, w[c * 4 + j], acc);
        }
    }
    float y = acc * sigmoidf_(acc);                    // SiLU
    int h = c >> 7, cl = c & 127;
    int p = TRANSPOSE ? ((cl & 15) * 8 + (cl >> 4)) : cl;
    outp[((size_t)(b * H_ + h) * T_ + t) * 128 + p] = f2bf(y);
}

// ---------------------------------------------------------------- gated delta-rule scan v4
// 256 blocks x 512 threads (8 waves). Block = (b,h) x 32 v-columns (vch 0..3).
// Per column: 16 lanes (one DPP row), 8 k-channels per lane (ch = sl + 16j) -> reduce is
// PURE-VALU row_allreduce16 (no LDS-pipe shfl). q,k staged bf16 in LDS (1 ds_read_b128
// each); d staged f32 split sdA/sdB (2x b128, 2-way-conflict-free, r1-verified layout).
// 8 waves/CU: LDS-pipe model 60cy/step/wave -> ~410us (vs r3 measured-bound 755, r5
// VALU-bound 874). All layout maps byte-identical to r1-verified kernel.
#define TB2 16
__global__ __launch_bounds__(512, 2) void kda_scan_k(const u16* __restrict__ qg,
                                                     const u16* __restrict__ kg,
                                                     const u16* __restrict__ vg,
                                                     const u16* __restrict__ ag,   // a pre-act bf16 (B*T,2048), r1 scan layout per head-block
                                                     const u16* __restrict__ bpg,  // beta pre-act bf16 (B*T,128)
                                                     const float* __restrict__ bav, // ba f32 (2048), ORIGINAL channel order
                                                     const float* __restrict__ bbv, // bb f32 (16)
                                                     u16* __restrict__ og) {
    const int blk = blockIdx.x;
    // XCD-clustered: xcd = blk&7 (round-robin dispatch); all 4 vch-blocks of a bh share one XCD
    const int xcd = blk & 7;
    const int ci  = (blk >> 3) & 7;
    const int vch = blk >> 6;                       // 0..3
    const int bh  = xcd * 8 + ci;
    const int tid = threadIdx.x;
    const int lane = tid & 63;
    const int w    = tid >> 6;                      // wave 0..7
    const int colIdx = w * 4 + (lane >> 4);         // 0..31 (v-column within block; DPP-row aligned)
    const int sl     = lane & 15;                   // k = sl + 16*j
    const int b = bh >> 4, h = bh & 15;

    __shared__ __align__(16) u16   sq[2][TB2][128];
    __shared__ __align__(16) u16   sk[2][TB2][128];
    __shared__ __align__(16) float sdA[2][TB2][64];   // decay f32, positions p&4==0 (j=0..3)
    __shared__ __align__(16) float sdB[2][TB2][64];   // decay f32, positions p&4==4 (j=4..7)
    __shared__ float sv[2][TB2][32];
    __shared__ float sb_[2][TB2];

    const u16* qb  = qg + (size_t)bh * T_ * 128;
    const u16* kb  = kg + (size_t)bh * T_ * 128;
    const u16* vst = vg + (size_t)bh * T_ * 128 + vch * 32 + (tid & 31);  // staging base
    const u16* ab  = ag + (size_t)b * T_ * 2048 + h * 128;
    const u16* bpb = bpg + (size_t)b * T_ * 128 + h;
    u16* op = og + (size_t)b * T_ * 2048 + h * 128 + vch * 32 + colIdx;

    // staging role: thread (ur, c4) covers scan-layout positions c4..c4+3 of timestep ur
    const int ur = tid >> 5;               // 0..15
    const int c4 = (tid & 31) * 4;         // c4&7 in {0,4}
    // position c4+e is original channel ch = ((c4&7)+e)*16 + (c4>>3)  (r1-verified)
    const int chb = c4 >> 3;
    const int jb  = c4 & 7;
    const float rba0 = bav[h * 128 + (jb + 0) * 16 + chb];
    const float rba1 = bav[h * 128 + (jb + 1) * 16 + chb];
    const float rba2 = bav[h * 128 + (jb + 2) * 16 + chb];
    const float rba3 = bav[h * 128 + (jb + 3) * 16 + chb];
    const float bbh = bbv[h];
    float* dst_d = (c4 & 4) ? &sdB[0][0][0] : &sdA[0][0][0];
    const int doff = ur * 64 + chb * 4;    // float offset within one pb-buffer
    const int dstride = TB2 * 64;          // floats per pb-buffer

    float S[8];
#pragma unroll
    for (int j = 0; j < 8; ++j) S[j] = 0.f;

    // tile-0 staging prefetch
    ushort4 rq = *(const ushort4*)(qb + (size_t)ur * 128 + c4);
    ushort4 rk = *(const ushort4*)(kb + (size_t)ur * 128 + c4);
    ushort4 ra = *(const ushort4*)(ab + (size_t)ur * 2048 + c4);
    u16 rv = vst[(size_t)ur * 128];
    float rbet = (tid < TB2) ? bf2f(bpb[(size_t)tid * 128]) : 0.f;

    const float scale = 0.08838834764831845f;  // 128^-0.5
    const int NM = T_ / TB2;
    for (int m = 0; m < NM; ++m) {
        const int pb = m & 1;
        float4 fd = {fmaxf(sigmoidf_(bf2f(ra.x) + rba0), 1e-6f),
                     fmaxf(sigmoidf_(bf2f(ra.y) + rba1), 1e-6f),
                     fmaxf(sigmoidf_(bf2f(ra.z) + rba2), 1e-6f),
                     fmaxf(sigmoidf_(bf2f(ra.w) + rba3), 1e-6f)};
        *(ushort4*)&sq[pb][ur][c4] = rq;
        *(ushort4*)&sk[pb][ur][c4] = rk;
        *(float4*)(dst_d + pb * dstride + doff) = fd;
        sv[pb][ur][tid & 31] = bf2f(rv);
        if (tid < TB2) sb_[pb][tid] = sigmoidf_(rbet + bbh);
        __syncthreads();
        if (m + 1 < NM) {
            size_t t0n = (size_t)(m + 1) * TB2;
            rq = *(const ushort4*)(qb + (t0n + ur) * 128 + c4);
            rk = *(const ushort4*)(kb + (t0n + ur) * 128 + c4);
            ra = *(const ushort4*)(ab + (t0n + ur) * 2048 + c4);
            rv = vst[(t0n + ur) * 128];
            if (tid < TB2) rbet = bf2f(bpb[(t0n + tid) * 128]);
        }
#pragma unroll
        for (int u = 0; u < TB2; ++u) {
            u16x8 q8 = *(const u16x8*)&sq[pb][u][sl * 8];
            u16x8 k8 = *(const u16x8*)&sk[pb][u][sl * 8];
            float4 dA = *(const float4*)&sdA[pb][u][sl * 4];
            float4 dB = *(const float4*)&sdB[pb][u][sl * 4];
            float fv  = sv[pb][u][colIdx];
            float sbv = sb_[pb][u];
            float qf[8], kf[8], dv[8];
#pragma unroll
            for (int j = 0; j < 8; ++j) { kf[j] = bf2f(k8[j]); qf[j] = bf2f(q8[j]); }
            dv[0] = dA.x; dv[1] = dA.y; dv[2] = dA.z; dv[3] = dA.w;
            dv[4] = dB.x; dv[5] = dB.y; dv[6] = dB.z; dv[7] = dB.w;
            float e0 = 0.f, e1 = 0.f;
#pragma unroll
            for (int j = 0; j < 8; j += 2) {
                S[j]     *= dv[j];     e0 = fmaf(kf[j],     S[j],     e0);
                S[j + 1] *= dv[j + 1]; e1 = fmaf(kf[j + 1], S[j + 1], e1);
            }
            float errp = row_allreduce16(e0 + e1);
            float uu = sbv * (fv - errp);
            float o0 = 0.f, o1 = 0.f;
#pragma unroll
            for (int j = 0; j < 8; j += 2) {
                S[j]     = fmaf(kf[j],     uu, S[j]);     o0 = fmaf(qf[j],     S[j],     o0);
                S[j + 1] = fmaf(kf[j + 1], uu, S[j + 1]); o1 = fmaf(qf[j + 1], S[j + 1], o1);
            }
            float outv = row_allreduce16(o0 + o1);
            if (sl == 0)
                op[(size_t)(m * TB2 + u) * 2048] = f2bf(scale * outv);
        }
        __syncthreads();
    }
}

// ---------------------------------------------------------------- per-head LayerNorm * sigmoid-gate -> bf16 act
__global__ __launch_bounds__(256) void ln_gate_k(const u16* __restrict__ o,
                                                 const u16* __restrict__ gpre,
                                                 const float* __restrict__ lnw,
                                                 const float* __restrict__ lnb,
                                                 u16* __restrict__ act) {
    int inst = blockIdx.x * 4 + (threadIdx.x >> 6);  // (b*T+t)*16 + h
    int lane = threadIdx.x & 63;
    int bt = inst >> 4, h = inst & 15;
    const u16* opr = o + (size_t)bt * 2048 + h * 128;
    ushort2 xr = *(const ushort2*)(opr + lane * 2);
    float x0 = bf2f(xr.x), x1 = bf2f(xr.y);
    float s  = x0 + x1;
    float ss = x0 * x0 + x1 * x1;
#pragma unroll
    for (int msk = 1; msk < 64; msk <<= 1) {
        s  += __shfl_xor(s, msk);
        ss += __shfl_xor(ss, msk);
    }
    float mu   = s * (1.f / 128.f);
    float var  = ss * (1.f / 128.f) - mu * mu;
    float rstd = rsqrtf(var + 1e-5f);
    const u16* gp = gpre + (size_t)bt * 2048 + h * 128 + lane * 2;
    u16* ap = act + (size_t)bt * 2048 + h * 128 + lane * 2;
#pragma unroll
    for (int e = 0; e < 2; ++e) {
        int v = lane * 2 + e;
        float xx = (e == 0) ? x0 : x1;
        float y = (xx - mu) * rstd * lnw[v] + lnb[v];
        float gate = sigmoidf_(bf2f(gp[e]));
        ap[e] = f2bf(y * gate);
    }
}

// ---------------------------------------------------------------- launch
// Tensors are FLOAT32 (per reference). bf16 only as internal GEMM operands.
// ws = 144.7 MB: Wslot(8M bf16) qpre/kpre/vpre/apre(32M bf16 each) bpre(2M).
// d_out (64MB f32) doubles as scratch: lo 32MB = xb (x in bf16), hi 32MB = qsc.
// Buffer lifetimes (stream-serialized):
//   gemms q,k,v,a,beta (read xb) -> conv q->qsc, k->ksc(=qpre), v->vsc(=kpre)
//   -> scan(qsc,ksc,vsc,apre,bpre)->ob(=vpre) -> gemm g (reads xb)->gpre(=qpre)
//   -> ln_gate(ob,gpre)->act(=kpre) -> gemm o (reads act)->d_out (f32).
extern "C" void kernel_launch(void* const* d_in, const int* in_sizes, int n_in,
                              void* d_out, int out_size, void* d_ws, size_t ws_size,
                              hipStream_t stream) {
    (void)in_sizes; (void)n_in; (void)out_size; (void)ws_size;
    const float* x   = (const float*)d_in[0];
    const float* Wq  = (const float*)d_in[1];
    const float* Wk  = (const float*)d_in[2];
    const float* Wv  = (const float*)d_in[3];
    const float* Wa  = (const float*)d_in[4];
    const float* ba  = (const float*)d_in[5];
    const float* Wb  = (const float*)d_in[6];
    const float* bbv = (const float*)d_in[7];
    const float* Wg  = (const float*)d_in[8];
    const float* Wo  = (const float*)d_in[9];
    const float* cqw = (const float*)d_in[10];
    const float* cqb = (const float*)d_in[11];
    const float* ckw = (const float*)d_in[12];
    const float* ckb = (const float*)d_in[13];
    const float* cvw = (const float*)d_in[14];
    const float* cvb = (const float*)d_in[15];
    const float* lnw = (const float*)d_in[16];
    const float* lnb = (const float*)d_in[17];
    float* out = (float*)d_out;

    char* p = (char*)d_ws;
    size_t off = 0;
    auto take = [&](size_t bytes) -> char* {
        char* r = p + off;
        off += (bytes + 255) & ~(size_t)255;
        return r;
    };
    u16* Wslot = (u16*)take((size_t)4194304 * 2);
    u16* qpre  = (u16*)take((size_t)16777216 * 2);
    u16* kpre  = (u16*)take((size_t)16777216 * 2);
    u16* vpre  = (u16*)take((size_t)16777216 * 2);
    u16* apre  = (u16*)take((size_t)16777216 * 2);
    u16* bpre  = (u16*)take((size_t)1048576 * 2);

    u16* xb  = (u16*)d_out;                 // lo 32MB of d_out
    u16* qsc = (u16*)d_out + 16777216;      // hi 32MB of d_out
    u16* ksc  = qpre;   // after conv-q
    u16* vsc  = kpre;   // after conv-k
    u16* ob   = vpre;   // after conv-v
    u16* gpre = qpre;   // after scan
    u16* act  = kpre;   // after scan (vsc dead)

    // x -> bf16 (into d_out lo half)
    cvt_bf16_k<<<16384, 256, 0, stream>>>(x, xb, 16777216);

    // projections: convert weight into Wslot, then GEMM (C = A @ B^T)
    cvt_bf16_k<<<4096, 256, 0, stream>>>(Wq, Wslot, 4194304);
    gemm_bt<u16, 0><<<dim3(64, 16), 256, 0, stream>>>(xb, Wslot, qpre, 2048, 2048);
    cvt_bf16_k<<<4096, 256, 0, stream>>>(Wk, Wslot, 4194304);
    gemm_bt<u16, 0><<<dim3(64, 16), 256, 0, stream>>>(xb, Wslot, kpre, 2048, 2048);
    cvt_bf16_k<<<4096, 256, 0, stream>>>(Wv, Wslot, 4194304);
    gemm_bt<u16, 0><<<dim3(64, 16), 256, 0, stream>>>(xb, Wslot, vpre, 2048, 2048);
    cvt_bf16_k<<<4096, 256, 0, stream>>>(Wa, Wslot, 4194304);
    gemm_bt<u16, 1><<<dim3(64, 16), 256, 0, stream>>>(xb, Wslot, apre, 2048, 2048);  // r1 scan layout
    pad_wb_k<<<1024, 256, 0, stream>>>(Wb, Wslot);
    gemm_bt<u16, 0><<<dim3(64, 1), 256, 0, stream>>>(xb, Wslot, bpre, 2048, 128);

    // conv + SiLU + layout change (q,k r1 scan layout; v standard)
    conv_silu_k<1><<<65536, 256, 0, stream>>>(qpre, cqw, cqb, qsc);
    conv_silu_k<1><<<65536, 256, 0, stream>>>(kpre, ckw, ckb, ksc);
    conv_silu_k<0><<<65536, 256, 0, stream>>>(vpre, cvw, cvb, vsc);

    // sequential gated delta-rule scan (decay/beta computed in-kernel)
    kda_scan_k<<<256, 512, 0, stream>>>(qsc, ksc, vsc, apre, bpre, ba, bbv, ob);

    // gate projection (deferred; xb still intact in d_out lo half)
    cvt_bf16_k<<<4096, 256, 0, stream>>>(Wg, Wslot, 4194304);
    gemm_bt<u16, 0><<<dim3(64, 16), 256, 0, stream>>>(xb, Wslot, gpre, 2048, 2048);

    // LayerNorm * gate -> bf16 activations
    ln_gate_k<<<32768, 256, 0, stream>>>(ob, gpre, lnw, lnb, act);

    // output projection -> f32 out (overwrites xb/qsc scratch)
    cvt_bf16_k<<<4096, 256, 0, stream>>>(Wo, Wslot, 4194304);
    gemm_bt<float, 0><<<dim3(64, 16), 256, 0, stream>>>(act, Wslot, out, 2048, 2048);
}

// Round 7
// 1661.499 us; speedup vs baseline: 1.1313x; 1.0196x over previous
//
#include <hip/hip_runtime.h>
#include <cstdint>
#include <cstddef>

#define B_ 4
#define T_ 2048
#define D_ 2048
#define H_ 16

typedef __bf16 bf16x8 __attribute__((ext_vector_type(8)));
typedef float  f32x4  __attribute__((ext_vector_type(4)));
typedef unsigned short u16;
typedef u16 u16x8 __attribute__((ext_vector_type(8)));

__device__ __forceinline__ u16 f2bf(float f) {
    union { float f; unsigned u; } v; v.f = f;
    unsigned r = v.u + 0x7FFFu + ((v.u >> 16) & 1u);
    return (u16)(r >> 16);
}
__device__ __forceinline__ float bf2f(u16 h) {
    union { unsigned u; float f; } v; v.u = ((unsigned)h) << 16;
    return v.f;
}
__device__ __forceinline__ float sigmoidf_(float x) {
    return 1.f / (1.f + __expf(-x));
}
__device__ __forceinline__ void async_load16(const void* g, void* l) {
    __builtin_amdgcn_global_load_lds(
        (const __attribute__((address_space(1))) void*)g,
        (__attribute__((address_space(3))) void*)l,
        16, 0, 0);
}

// 16-lane all-reduce sum via DPP (within each DPP row of 16 lanes)
// quad_perm xor1 -> quad_perm xor2 -> row_mirror -> row_half_mirror  (HW-verified r1/r3/r5/r6)
__device__ __forceinline__ float row_allreduce16(float x) {
    int v;
    v = __builtin_amdgcn_update_dpp(0, __builtin_bit_cast(int, x), 0xB1, 0xF, 0xF, true);
    x += __builtin_bit_cast(float, v);
    v = __builtin_amdgcn_update_dpp(0, __builtin_bit_cast(int, x), 0x4E, 0xF, 0xF, true);
    x += __builtin_bit_cast(float, v);
    v = __builtin_amdgcn_update_dpp(0, __builtin_bit_cast(int, x), 0x140, 0xF, 0xF, true);
    x += __builtin_bit_cast(float, v);
    v = __builtin_amdgcn_update_dpp(0, __builtin_bit_cast(int, x), 0x141, 0xF, 0xF, true);
    x += __builtin_bit_cast(float, v);
    return x;
}

// ---------------------------------------------------------------- f32 -> bf16 convert (x4 vectorized; n % 4 == 0)
__global__ void cvt_bf16_k(const float* __restrict__ s, u16* __restrict__ d, int n) {
    int i = blockIdx.x * 256 + threadIdx.x;   // element-group index
    if (i * 4 < n) {
        float4 v = *(const float4*)(s + (size_t)i * 4);
        ushort4 o = {f2bf(v.x), f2bf(v.y), f2bf(v.z), f2bf(v.w)};
        *(ushort4*)(d + (size_t)i * 4) = o;
    }
}

// ---------------------------------------------------------------- Wb pad: f32 (16,2048) -> bf16 (128,2048), rows 16..127 zero
__global__ void pad_wb_k(const float* __restrict__ Wb, u16* __restrict__ d) {
    int i = blockIdx.x * 256 + threadIdx.x;   // 262144 total
    d[i] = (i < 32768) ? f2bf(Wb[i]) : (u16)0;
}

// ---------------------------------------------------------------- GEMM (C = A * B^T), bf16 in, m97-style
// PERM=1 (r1-verified): permute output column within each 128-block: ch -> (ch&15)*8 + (ch>>4)
// (scan layout: lane sl's 8 channels {sl,sl+16,..,sl+112} land contiguous as 16B)
__device__ __forceinline__ void store_c(float* p, float v) { *p = v; }
__device__ __forceinline__ void store_c(u16* p, float v) { *p = f2bf(v); }

template <typename OutT, int PERM>
__global__ __launch_bounds__(256) void gemm_bt(const u16* __restrict__ A,
                                               const u16* __restrict__ Bm,
                                               OutT* __restrict__ C, int K, int ldc) {
    __shared__ __align__(16) u16 smA[128 * 64];
    __shared__ __align__(16) u16 smB[128 * 64];
    const int tid  = threadIdx.x;
    const int lane = tid & 63;
    const int w    = tid >> 6;
    const int wm   = (w >> 1) * 64;
    const int wn   = (w & 1) * 64;
    const int bm   = blockIdx.x, bn = blockIdx.y;

    f32x4 acc[4][4];
#pragma unroll
    for (int i = 0; i < 4; ++i)
#pragma unroll
        for (int j = 0; j < 4; ++j) acc[i][j] = (f32x4){0.f, 0.f, 0.f, 0.f};

    const int rr = tid >> 3;            // 0..31
    const int cc = (tid & 7) * 8;       // 0..56
    const u16* Ag = A + (size_t)(bm * 128) * K;
    const u16* Bg = Bm + (size_t)(bn * 128) * K;

    for (int k0 = 0; k0 < K; k0 += 64) {
#pragma unroll
        for (int it = 0; it < 4; ++it) {
            async_load16(Ag + (size_t)(it * 32 + rr) * K + (k0 + cc), &smA[(it * 256 + tid) * 8]);
            async_load16(Bg + (size_t)(it * 32 + rr) * K + (k0 + cc), &smB[(it * 256 + tid) * 8]);
        }
        __syncthreads();
#pragma unroll
        for (int kk = 0; kk < 64; kk += 32) {
            bf16x8 af[4], bfr[4];
            const int qoff = kk + ((lane >> 4) * 8);
#pragma unroll
            for (int mi = 0; mi < 4; ++mi)
                af[mi] = *(const bf16x8*)&smA[(wm + mi * 16 + (lane & 15)) * 64 + qoff];
#pragma unroll
            for (int ni = 0; ni < 4; ++ni)
                bfr[ni] = *(const bf16x8*)&smB[(wn + ni * 16 + (lane & 15)) * 64 + qoff];
#pragma unroll
            for (int mi = 0; mi < 4; ++mi)
#pragma unroll
                for (int ni = 0; ni < 4; ++ni)
                    acc[mi][ni] = __builtin_amdgcn_mfma_f32_16x16x32_bf16(af[mi], bfr[ni], acc[mi][ni], 0, 0, 0);
        }
        __syncthreads();
    }

#pragma unroll
    for (int mi = 0; mi < 4; ++mi) {
        const int row0 = bm * 128 + wm + mi * 16 + ((lane >> 4) * 4);
#pragma unroll
        for (int ni = 0; ni < 4; ++ni) {
            int colg = bn * 128 + wn + ni * 16 + (lane & 15);
            if (PERM) colg = (colg & ~127) | (((colg & 15) << 3) | ((colg >> 4) & 7));
#pragma unroll
            for (int rg = 0; rg < 4; ++rg)
                store_c(&C[(size_t)(row0 + rg) * ldc + colg], acc[mi][ni][rg]);
        }
    }
}

// ---------------------------------------------------------------- causal depthwise conv(K=4) + bias + SiLU
// in : pre bf16 (B*T, 2048), col = h*128+c ; w/bias f32
// out: bf16 [(b*H+h)*T + t]*128 + p ; p = cl (TRANSPOSE=0) or r1 scan layout (TRANSPOSE=1)
template <int TRANSPOSE>
__global__ void conv_silu_k(const u16* __restrict__ pre,
                            const float* __restrict__ w, const float* __restrict__ bias,
                            u16* __restrict__ outp) {
    int idx = blockIdx.x * 256 + threadIdx.x;          // B*T*2048 = 2^24 exact
    int c = idx & 2047;
    int t = (idx >> 11) & (T_ - 1);
    int b = idx >> 22;
    const u16* base = pre + (size_t)(b * T_ + t) * 2048 + c;
    float acc = bias[c];
#pragma unroll
    for (int j = 0; j < 4; ++j) {
        int tt = t - 3 + j;
        if (tt >= 0) {
            float xv = bf2f(base[(ptrdiff_t)(j - 3) * 2048]);
            acc = fmaf(xv, w[c * 4 + j], acc);
        }
    }
    float y = acc * sigmoidf_(acc);                    // SiLU
    int h = c >> 7, cl = c & 127;
    int p = TRANSPOSE ? ((cl & 15) * 8 + (cl >> 4)) : cl;
    outp[((size_t)(b * H_ + h) * T_ + t) * 128 + p] = f2bf(y);
}

// ---------------------------------------------------------------- gated delta-rule scan v5
// Identical structure/layout/numerics to r6-verified v4 (256 blk x 512 thr, 16-lane DPP
// groups, bf16 q/k + f32 d in LDS), with one change: SOFTWARE-PIPELINED inner loop.
// r6 showed VGPR=40 -> compiler couldn't prefetch; each step exposed ds_read latency on
// top of the 480cy/step/CU LDS-pipe floor (632us vs 410us model). Explicit next-step
// registers (rotated with compile-time indices under full unroll) put step u+1's LDS
// reads in flight during step u's reduce chains.
#define TB2 16
__global__ __launch_bounds__(512, 2) void kda_scan_k(const u16* __restrict__ qg,
                                                     const u16* __restrict__ kg,
                                                     const u16* __restrict__ vg,
                                                     const u16* __restrict__ ag,   // a pre-act bf16 (B*T,2048), r1 scan layout per head-block
                                                     const u16* __restrict__ bpg,  // beta pre-act bf16 (B*T,128)
                                                     const float* __restrict__ bav, // ba f32 (2048), ORIGINAL channel order
                                                     const float* __restrict__ bbv, // bb f32 (16)
                                                     u16* __restrict__ og) {
    const int blk = blockIdx.x;
    // XCD-clustered: xcd = blk&7 (round-robin dispatch); all 4 vch-blocks of a bh share one XCD
    const int xcd = blk & 7;
    const int ci  = (blk >> 3) & 7;
    const int vch = blk >> 6;                       // 0..3
    const int bh  = xcd * 8 + ci;
    const int tid = threadIdx.x;
    const int lane = tid & 63;
    const int w    = tid >> 6;                      // wave 0..7
    const int colIdx = w * 4 + (lane >> 4);         // 0..31 (v-column within block; DPP-row aligned)
    const int sl     = lane & 15;                   // k = sl + 16*j
    const int b = bh >> 4, h = bh & 15;

    __shared__ __align__(16) u16   sq[2][TB2][128];
    __shared__ __align__(16) u16   sk[2][TB2][128];
    __shared__ __align__(16) float sdA[2][TB2][64];   // decay f32, positions p&4==0 (j=0..3)
    __shared__ __align__(16) float sdB[2][TB2][64];   // decay f32, positions p&4==4 (j=4..7)
    __shared__ float sv[2][TB2][32];
    __shared__ float sb_[2][TB2];

    const u16* qb  = qg + (size_t)bh * T_ * 128;
    const u16* kb  = kg + (size_t)bh * T_ * 128;
    const u16* vst = vg + (size_t)bh * T_ * 128 + vch * 32 + (tid & 31);  // staging base
    const u16* ab  = ag + (size_t)b * T_ * 2048 + h * 128;
    const u16* bpb = bpg + (size_t)b * T_ * 128 + h;
    u16* op = og + (size_t)b * T_ * 2048 + h * 128 + vch * 32 + colIdx;

    // staging role: thread (ur, c4) covers scan-layout positions c4..c4+3 of timestep ur
    const int ur = tid >> 5;               // 0..15
    const int c4 = (tid & 31) * 4;         // c4&7 in {0,4}
    // position c4+e is original channel ch = ((c4&7)+e)*16 + (c4>>3)  (r1-verified)
    const int chb = c4 >> 3;
    const int jb  = c4 & 7;
    const float rba0 = bav[h * 128 + (jb + 0) * 16 + chb];
    const float rba1 = bav[h * 128 + (jb + 1) * 16 + chb];
    const float rba2 = bav[h * 128 + (jb + 2) * 16 + chb];
    const float rba3 = bav[h * 128 + (jb + 3) * 16 + chb];
    const float bbh = bbv[h];
    float* dst_d = (c4 & 4) ? &sdB[0][0][0] : &sdA[0][0][0];
    const int doff = ur * 64 + chb * 4;    // float offset within one pb-buffer
    const int dstride = TB2 * 64;          // floats per pb-buffer

    float S[8];
#pragma unroll
    for (int j = 0; j < 8; ++j) S[j] = 0.f;

    // tile-0 staging prefetch
    ushort4 rq = *(const ushort4*)(qb + (size_t)ur * 128 + c4);
    ushort4 rk = *(const ushort4*)(kb + (size_t)ur * 128 + c4);
    ushort4 ra = *(const ushort4*)(ab + (size_t)ur * 2048 + c4);
    u16 rv = vst[(size_t)ur * 128];
    float rbet = (tid < TB2) ? bf2f(bpb[(size_t)tid * 128]) : 0.f;

    const float scale = 0.08838834764831845f;  // 128^-0.5
    const int NM = T_ / TB2;
    for (int m = 0; m < NM; ++m) {
        const int pb = m & 1;
        float4 fd = {fmaxf(sigmoidf_(bf2f(ra.x) + rba0), 1e-6f),
                     fmaxf(sigmoidf_(bf2f(ra.y) + rba1), 1e-6f),
                     fmaxf(sigmoidf_(bf2f(ra.z) + rba2), 1e-6f),
                     fmaxf(sigmoidf_(bf2f(ra.w) + rba3), 1e-6f)};
        *(ushort4*)&sq[pb][ur][c4] = rq;
        *(ushort4*)&sk[pb][ur][c4] = rk;
        *(float4*)(dst_d + pb * dstride + doff) = fd;
        sv[pb][ur][tid & 31] = bf2f(rv);
        if (tid < TB2) sb_[pb][tid] = sigmoidf_(rbet + bbh);
        __syncthreads();
        if (m + 1 < NM) {
            size_t t0n = (size_t)(m + 1) * TB2;
            rq = *(const ushort4*)(qb + (t0n + ur) * 128 + c4);
            rk = *(const ushort4*)(kb + (t0n + ur) * 128 + c4);
            ra = *(const ushort4*)(ab + (t0n + ur) * 2048 + c4);
            rv = vst[(t0n + ur) * 128];
            if (tid < TB2) rbet = bf2f(bpb[(t0n + tid) * 128]);
        }
        // software pipeline: preload step 0, prefetch step u+1 during step u
        u16x8  q8c = *(const u16x8*)&sq[pb][0][sl * 8];
        u16x8  k8c = *(const u16x8*)&sk[pb][0][sl * 8];
        float4 dAc = *(const float4*)&sdA[pb][0][sl * 4];
        float4 dBc = *(const float4*)&sdB[pb][0][sl * 4];
        float  fvc = sv[pb][0][colIdx];
        float  sbc = sb_[pb][0];
#pragma unroll
        for (int u = 0; u < TB2; ++u) {
            u16x8 q8n, k8n; float4 dAn, dBn; float fvn = 0.f, sbn = 0.f;
            if (u + 1 < TB2) {
                q8n = *(const u16x8*)&sq[pb][u + 1][sl * 8];
                k8n = *(const u16x8*)&sk[pb][u + 1][sl * 8];
                dAn = *(const float4*)&sdA[pb][u + 1][sl * 4];
                dBn = *(const float4*)&sdB[pb][u + 1][sl * 4];
                fvn = sv[pb][u + 1][colIdx];
                sbn = sb_[pb][u + 1];
            }
            float qf[8], kf[8], dv[8];
#pragma unroll
            for (int j = 0; j < 8; ++j) { kf[j] = bf2f(k8c[j]); qf[j] = bf2f(q8c[j]); }
            dv[0] = dAc.x; dv[1] = dAc.y; dv[2] = dAc.z; dv[3] = dAc.w;
            dv[4] = dBc.x; dv[5] = dBc.y; dv[6] = dBc.z; dv[7] = dBc.w;
            float e0 = 0.f, e1 = 0.f;
#pragma unroll
            for (int j = 0; j < 8; j += 2) {
                S[j]     *= dv[j];     e0 = fmaf(kf[j],     S[j],     e0);
                S[j + 1] *= dv[j + 1]; e1 = fmaf(kf[j + 1], S[j + 1], e1);
            }
            float errp = row_allreduce16(e0 + e1);
            float uu = sbc * (fvc - errp);
            float o0 = 0.f, o1 = 0.f;
#pragma unroll
            for (int j = 0; j < 8; j += 2) {
                S[j]     = fmaf(kf[j],     uu, S[j]);     o0 = fmaf(qf[j],     S[j],     o0);
                S[j + 1] = fmaf(kf[j + 1], uu, S[j + 1]); o1 = fmaf(qf[j + 1], S[j + 1], o1);
            }
            float outv = row_allreduce16(o0 + o1);
            if (sl == 0)
                op[(size_t)(m * TB2 + u) * 2048] = f2bf(scale * outv);
            if (u + 1 < TB2) {
                q8c = q8n; k8c = k8n; dAc = dAn; dBc = dBn; fvc = fvn; sbc = sbn;
            }
        }
        __syncthreads();
    }
}

// ---------------------------------------------------------------- per-head LayerNorm * sigmoid-gate -> bf16 act
__global__ __launch_bounds__(256) void ln_gate_k(const u16* __restrict__ o,
                                                 const u16* __restrict__ gpre,
                                                 const float* __restrict__ lnw,
                                                 const float* __restrict__ lnb,
                                                 u16* __restrict__ act) {
    int inst = blockIdx.x * 4 + (threadIdx.x >> 6);  // (b*T+t)*16 + h
    int lane = threadIdx.x & 63;
    int bt = inst >> 4, h = inst & 15;
    const u16* opr = o + (size_t)bt * 2048 + h * 128;
    ushort2 xr = *(const ushort2*)(opr + lane * 2);
    float x0 = bf2f(xr.x), x1 = bf2f(xr.y);
    float s  = x0 + x1;
    float ss = x0 * x0 + x1 * x1;
#pragma unroll
    for (int msk = 1; msk < 64; msk <<= 1) {
        s  += __shfl_xor(s, msk);
        ss += __shfl_xor(ss, msk);
    }
    float mu   = s * (1.f / 128.f);
    float var  = ss * (1.f / 128.f) - mu * mu;
    float rstd = rsqrtf(var + 1e-5f);
    const u16* gp = gpre + (size_t)bt * 2048 + h * 128 + lane * 2;
    u16* ap = act + (size_t)bt * 2048 + h * 128 + lane * 2;
#pragma unroll
    for (int e = 0; e < 2; ++e) {
        int v = lane * 2 + e;
        float xx = (e == 0) ? x0 : x1;
        float y = (xx - mu) * rstd * lnw[v] + lnb[v];
        float gate = sigmoidf_(bf2f(gp[e]));
        ap[e] = f2bf(y * gate);
    }
}

// ---------------------------------------------------------------- launch
// Tensors are FLOAT32 (per reference). bf16 only as internal GEMM operands.
// ws = 144.7 MB: Wslot(8M bf16) qpre/kpre/vpre/apre(32M bf16 each) bpre(2M).
// d_out (64MB f32) doubles as scratch: lo 32MB = xb (x in bf16), hi 32MB = qsc.
// Buffer lifetimes (stream-serialized):
//   gemms q,k,v,a,beta (read xb) -> conv q->qsc, k->ksc(=qpre), v->vsc(=kpre)
//   -> scan(qsc,ksc,vsc,apre,bpre)->ob(=vpre) -> gemm g (reads xb)->gpre(=qpre)
//   -> ln_gate(ob,gpre)->act(=kpre) -> gemm o (reads act)->d_out (f32).
extern "C" void kernel_launch(void* const* d_in, const int* in_sizes, int n_in,
                              void* d_out, int out_size, void* d_ws, size_t ws_size,
                              hipStream_t stream) {
    (void)in_sizes; (void)n_in; (void)out_size; (void)ws_size;
    const float* x   = (const float*)d_in[0];
    const float* Wq  = (const float*)d_in[1];
    const float* Wk  = (const float*)d_in[2];
    const float* Wv  = (const float*)d_in[3];
    const float* Wa  = (const float*)d_in[4];
    const float* ba  = (const float*)d_in[5];
    const float* Wb  = (const float*)d_in[6];
    const float* bbv = (const float*)d_in[7];
    const float* Wg  = (const float*)d_in[8];
    const float* Wo  = (const float*)d_in[9];
    const float* cqw = (const float*)d_in[10];
    const float* cqb = (const float*)d_in[11];
    const float* ckw = (const float*)d_in[12];
    const float* ckb = (const float*)d_in[13];
    const float* cvw = (const float*)d_in[14];
    const float* cvb = (const float*)d_in[15];
    const float* lnw = (const float*)d_in[16];
    const float* lnb = (const float*)d_in[17];
    float* out = (float*)d_out;

    char* p = (char*)d_ws;
    size_t off = 0;
    auto take = [&](size_t bytes) -> char* {
        char* r = p + off;
        off += (bytes + 255) & ~(size_t)255;
        return r;
    };
    u16* Wslot = (u16*)take((size_t)4194304 * 2);
    u16* qpre  = (u16*)take((size_t)16777216 * 2);
    u16* kpre  = (u16*)take((size_t)16777216 * 2);
    u16* vpre  = (u16*)take((size_t)16777216 * 2);
    u16* apre  = (u16*)take((size_t)16777216 * 2);
    u16* bpre  = (u16*)take((size_t)1048576 * 2);

    u16* xb  = (u16*)d_out;                 // lo 32MB of d_out
    u16* qsc = (u16*)d_out + 16777216;      // hi 32MB of d_out
    u16* ksc  = qpre;   // after conv-q
    u16* vsc  = kpre;   // after conv-k
    u16* ob   = vpre;   // after conv-v
    u16* gpre = qpre;   // after scan
    u16* act  = kpre;   // after scan (vsc dead)

    // x -> bf16 (into d_out lo half)
    cvt_bf16_k<<<16384, 256, 0, stream>>>(x, xb, 16777216);

    // projections: convert weight into Wslot, then GEMM (C = A @ B^T)
    cvt_bf16_k<<<4096, 256, 0, stream>>>(Wq, Wslot, 4194304);
    gemm_bt<u16, 0><<<dim3(64, 16), 256, 0, stream>>>(xb, Wslot, qpre, 2048, 2048);
    cvt_bf16_k<<<4096, 256, 0, stream>>>(Wk, Wslot, 4194304);
    gemm_bt<u16, 0><<<dim3(64, 16), 256, 0, stream>>>(xb, Wslot, kpre, 2048, 2048);
    cvt_bf16_k<<<4096, 256, 0, stream>>>(Wv, Wslot, 4194304);
    gemm_bt<u16, 0><<<dim3(64, 16), 256, 0, stream>>>(xb, Wslot, vpre, 2048, 2048);
    cvt_bf16_k<<<4096, 256, 0, stream>>>(Wa, Wslot, 4194304);
    gemm_bt<u16, 1><<<dim3(64, 16), 256, 0, stream>>>(xb, Wslot, apre, 2048, 2048);  // r1 scan layout
    pad_wb_k<<<1024, 256, 0, stream>>>(Wb, Wslot);
    gemm_bt<u16, 0><<<dim3(64, 1), 256, 0, stream>>>(xb, Wslot, bpre, 2048, 128);

    // conv + SiLU + layout change (q,k r1 scan layout; v standard)
    conv_silu_k<1><<<65536, 256, 0, stream>>>(qpre, cqw, cqb, qsc);
    conv_silu_k<1><<<65536, 256, 0, stream>>>(kpre, ckw, ckb, ksc);
    conv_silu_k<0><<<65536, 256, 0, stream>>>(vpre, cvw, cvb, vsc);

    // sequential gated delta-rule scan (decay/beta computed in-kernel)
    kda_scan_k<<<256, 512, 0, stream>>>(qsc, ksc, vsc, apre, bpre, ba, bbv, ob);

    // gate projection (deferred; xb still intact in d_out lo half)
    cvt_bf16_k<<<4096, 256, 0, stream>>>(Wg, Wslot, 4194304);
    gemm_bt<u16, 0><<<dim3(64, 16), 256, 0, stream>>>(xb, Wslot, gpre, 2048, 2048);

    // LayerNorm * gate -> bf16 activations
    ln_gate_k<<<32768, 256, 0, stream>>>(ob, gpre, lnw, lnb, act);

    // output projection -> f32 out (overwrites xb/qsc scratch)
    cvt_bf16_k<<<4096, 256, 0, stream>>>(Wo, Wslot, 4194304);
    gemm_bt<float, 0><<<dim3(64, 16), 256, 0, stream>>>(act, Wslot, out, 2048, 2048);
}